// Round 2
// baseline (438.372 us; speedup 1.0000x reference)
//
#include <hip/hip_runtime.h>
#include <math.h>

#define NPOS 131072  // 8*128*128 spatial positions per (b, channel)

// ---------------------------------------------------------------------------
// k_pw: pointwise 64-out-channel group g: pre[b][o][p] = sum_k W[g*64+o][k] x[b][k][p]
// grid (512, 2), block 256.
// ---------------------------------------------------------------------------
__global__ __launch_bounds__(256) void k_pw(const float* __restrict__ x,
                                            const float* __restrict__ w_qkv,
                                            float* __restrict__ pre, int g) {
  const int p = blockIdx.x * 256 + threadIdx.x;
  const int b = blockIdx.y;
  __shared__ __align__(16) float wlT[64 * 64];  // [k][o]
  for (int i = threadIdx.x; i < 4096; i += 256) {
    int o = i >> 6, k = i & 63;
    wlT[k * 64 + o] = w_qkv[(g * 64 + o) * 64 + k];
  }
  __syncthreads();
  float acc[64];
#pragma unroll
  for (int o = 0; o < 64; ++o) acc[o] = 0.f;
  const float* xb = x + ((size_t)b * 64) * NPOS + p;
  for (int k = 0; k < 64; ++k) {
    float xv = xb[(size_t)k * NPOS];
    const float4* w4 = (const float4*)&wlT[k * 64];
#pragma unroll
    for (int o4 = 0; o4 < 16; ++o4) {
      float4 wv = w4[o4];
      acc[o4 * 4 + 0] = fmaf(wv.x, xv, acc[o4 * 4 + 0]);
      acc[o4 * 4 + 1] = fmaf(wv.y, xv, acc[o4 * 4 + 1]);
      acc[o4 * 4 + 2] = fmaf(wv.z, xv, acc[o4 * 4 + 2]);
      acc[o4 * 4 + 3] = fmaf(wv.w, xv, acc[o4 * 4 + 3]);
    }
  }
  float* ob = pre + ((size_t)b * 64) * NPOS + p;
#pragma unroll
  for (int o = 0; o < 64; ++o) ob[(size_t)o * NPOS] = acc[o];
}

// ---------------------------------------------------------------------------
// k_dw: depthwise 3x3x3 SAME on a 64-channel group (weights rows g*64..g*64+63).
// Input/output layout [(b*64+c)*NPOS]. Optionally emits per-block sum of
// squares (for q-norms): nqp[(b*64+c)*64 + blk].
// grid (4, 16, 128), block (32, 8).
// ---------------------------------------------------------------------------
__global__ __launch_bounds__(256) void k_dw(const float* __restrict__ pre,
                                            const float* __restrict__ w_dw,
                                            float* __restrict__ conv,
                                            float* __restrict__ nqp, int g) {
  const int b = blockIdx.z >> 6;
  const int c = blockIdx.z & 63;
  const int h0 = blockIdx.y * 8;
  const int w0 = blockIdx.x * 32;
  __shared__ float t[10][10][34];
  __shared__ float red[4];
  const float* in = pre + ((size_t)b * 64 + c) * NPOS;
  const int tid = threadIdx.y * 32 + threadIdx.x;
  for (int i = tid; i < 3400; i += 256) {
    int wl = i % 34, r = i / 34, hl = r % 10, dl = r / 10;
    int dd = dl - 1, hh = h0 + hl - 1, ww = w0 + wl - 1;
    float v = 0.f;
    if (dd >= 0 && dd < 8 && hh >= 0 && hh < 128 && ww >= 0 && ww < 128)
      v = in[((size_t)dd * 128 + hh) * 128 + ww];
    t[dl][hl][wl] = v;
  }
  float wk[27];
#pragma unroll
  for (int i = 0; i < 27; ++i) wk[i] = w_dw[(g * 64 + c) * 27 + i];
  __syncthreads();
  const int wl = threadIdx.x, hl = threadIdx.y;
  float* outp = conv + ((size_t)b * 64 + c) * NPOS + (size_t)(h0 + hl) * 128 + (w0 + wl);
  float nsum = 0.f;
#pragma unroll
  for (int d = 0; d < 8; ++d) {
    float acc = 0.f;
#pragma unroll
    for (int kd = 0; kd < 3; ++kd)
#pragma unroll
      for (int kh = 0; kh < 3; ++kh)
#pragma unroll
        for (int kw = 0; kw < 3; ++kw)
          acc = fmaf(t[d + kd][hl + kh][wl + kw], wk[(kd * 3 + kh) * 3 + kw], acc);
    outp[(size_t)d * 128 * 128] = acc;
    nsum = fmaf(acc, acc, nsum);
  }
  if (nqp) {
    const int lane = tid & 63, wv = tid >> 6;
    float v = nsum;
    v += __shfl_down(v, 32); v += __shfl_down(v, 16); v += __shfl_down(v, 8);
    v += __shfl_down(v, 4);  v += __shfl_down(v, 2);  v += __shfl_down(v, 1);
    if (lane == 0) red[wv] = v;
    __syncthreads();
    if (tid == 0) {
      const int blk = blockIdx.y * 4 + blockIdx.x;  // 64 spatial blocks
      nqp[((size_t)b * 64 + c) * 64 + blk] = red[0] + red[1] + red[2] + red[3];
    }
  }
}

// ---------------------------------------------------------------------------
// k_dwk_gram: depthwise-conv the 8 k-channels of one head (from kpre) and fold
// against qconv at the same positions -> per-block partial S[8][8] (q x k) and
// nk[8]. partial4[((bh)*64 + blk)*72 + i].
// grid (4, 16, 16), block (32, 8).
// ---------------------------------------------------------------------------
__global__ __launch_bounds__(256) void k_dwk_gram(const float* __restrict__ kpre,
                                                  const float* __restrict__ qconv,
                                                  const float* __restrict__ w_dw,
                                                  float* __restrict__ partial4) {
  const int z = blockIdx.z;  // b*8 + head
  const int b = z >> 3, head = z & 7;
  const int h0 = blockIdx.y * 8;
  const int w0 = blockIdx.x * 32;
  const int tx = threadIdx.x, ty = threadIdx.y;
  const int tid = ty * 32 + tx;
  __shared__ float t[10][10][34];
  __shared__ float red[4][72];

  // load q values at this block's 8x32 column across all 8 d and 8 head-channels
  float qv[64];  // [c][d]
  {
    const float* qb = qconv + ((size_t)b * 64 + head * 8) * NPOS +
                      (size_t)(h0 + ty) * 128 + (w0 + tx);
#pragma unroll
    for (int c = 0; c < 8; ++c)
#pragma unroll
      for (int d = 0; d < 8; ++d)
        qv[c * 8 + d] = qb[(size_t)c * NPOS + (size_t)d * 16384];
  }
  float S[64], nk[8];
#pragma unroll
  for (int i = 0; i < 64; ++i) S[i] = 0.f;

  for (int cc = 0; cc < 8; ++cc) {
    const int ch = head * 8 + cc;            // k-local channel 0..63
    const float* in = kpre + ((size_t)b * 64 + ch) * NPOS;
    __syncthreads();  // previous iteration done reading t
    for (int i = tid; i < 3400; i += 256) {
      int wl = i % 34, r = i / 34, hl = r % 10, dl = r / 10;
      int dd = dl - 1, hh = h0 + hl - 1, ww = w0 + wl - 1;
      float v = 0.f;
      if (dd >= 0 && dd < 8 && hh >= 0 && hh < 128 && ww >= 0 && ww < 128)
        v = in[((size_t)dd * 128 + hh) * 128 + ww];
      t[dl][hl][wl] = v;
    }
    float wk[27];
#pragma unroll
    for (int i = 0; i < 27; ++i) wk[i] = w_dw[(64 + ch) * 27 + i];
    __syncthreads();
    float nkc = 0.f;
#pragma unroll
    for (int d = 0; d < 8; ++d) {
      float acc = 0.f;
#pragma unroll
      for (int kd = 0; kd < 3; ++kd)
#pragma unroll
        for (int kh = 0; kh < 3; ++kh)
#pragma unroll
          for (int kw = 0; kw < 3; ++kw)
            acc = fmaf(t[d + kd][ty + kh][tx + kw], wk[(kd * 3 + kh) * 3 + kw], acc);
      nkc = fmaf(acc, acc, nkc);
#pragma unroll
      for (int c = 0; c < 8; ++c)
        S[c * 8 + cc] = fmaf(qv[c * 8 + d], acc, S[c * 8 + cc]);
    }
    nk[cc] = nkc;
  }
  const int lane = tid & 63, wv = tid >> 6;
#pragma unroll
  for (int i = 0; i < 72; ++i) {
    float v = (i < 64) ? S[i] : nk[i - 64];
    v += __shfl_down(v, 32); v += __shfl_down(v, 16); v += __shfl_down(v, 8);
    v += __shfl_down(v, 4);  v += __shfl_down(v, 2);  v += __shfl_down(v, 1);
    if (lane == 0) red[wv][i] = v;
  }
  __syncthreads();
  if (tid < 72) {
    float s = red[0][tid] + red[1][tid] + red[2][tid] + red[3][tid];
    const int blk = blockIdx.y * 4 + blockIdx.x;  // 64 spatial blocks
    partial4[(((size_t)z) * 64 + blk) * 72 + tid] = s;
  }
}

// ---------------------------------------------------------------------------
// k_attn: reduce partials, l2-normalize, temperature, softmax -> A[bh][c][e].
// grid 16, block 128.
// ---------------------------------------------------------------------------
__global__ void k_attn(const float* __restrict__ partial4, const float* __restrict__ nqp,
                       const float* __restrict__ temp, float* __restrict__ A) {
  const int bh = blockIdx.x;
  const int b = bh >> 3, head = bh & 7;
  const int tid = threadIdx.x;
  __shared__ float sums[80];
  if (tid < 72) {
    float s = 0.f;
    const float* pp = partial4 + (size_t)bh * 64 * 72 + tid;
    for (int j = 0; j < 64; ++j) s += pp[j * 72];
    sums[tid] = s;  // [0:64) S, [64:72) nk
  } else if (tid < 80) {
    const int c = tid - 72;
    float s = 0.f;
    const float* pp = nqp + ((size_t)b * 64 + head * 8 + c) * 64;
    for (int j = 0; j < 64; ++j) s += pp[j];
    sums[tid] = s;  // [72:80) nq
  }
  __syncthreads();
  if (tid < 8) {
    const int c = tid;
    float tp = temp[head];
    float qd = fmaxf(sqrtf(sums[72 + c]), 1e-12f);
    float vals[8];
    float mx = -1e30f;
#pragma unroll
    for (int e = 0; e < 8; ++e) {
      float kd = fmaxf(sqrtf(sums[64 + e]), 1e-12f);
      vals[e] = sums[c * 8 + e] / (qd * kd) * tp;
      mx = fmaxf(mx, vals[e]);
    }
    float den = 0.f;
#pragma unroll
    for (int e = 0; e < 8; ++e) { vals[e] = expf(vals[e] - mx); den += vals[e]; }
#pragma unroll
    for (int e = 0; e < 8; ++e) A[bh * 64 + c * 8 + e] = vals[e] / den;
  }
}

// ---------------------------------------------------------------------------
// k_M: M_b[o][hg*8+j] = sum_i Wp[o][hg*8+i] * A[b][hg][i][j].  grid 2, block 256.
// ---------------------------------------------------------------------------
__global__ void k_M(const float* __restrict__ w_proj, const float* __restrict__ A,
                    float* __restrict__ M) {
  const int b = blockIdx.x;
  for (int e = threadIdx.x; e < 4096; e += 256) {
    int o = e >> 6, gch = e & 63;
    int hg = gch >> 3, j = gch & 7;
    float s = 0.f;
#pragma unroll
    for (int i = 0; i < 8; ++i)
      s += w_proj[o * 64 + hg * 8 + i] * A[(b * 8 + hg) * 64 + i * 8 + j];
    M[b * 4096 + e] = s;
  }
}

// ---------------------------------------------------------------------------
// k_out: out[b][o][p] = sum_g M_b[o][g] * vconv[b][g][p]. grid (512, 2), block 256.
// ---------------------------------------------------------------------------
__global__ __launch_bounds__(256) void k_out(const float* __restrict__ vconv,
                                             const float* __restrict__ M,
                                             float* __restrict__ out) {
  const int p = blockIdx.x * 256 + threadIdx.x;
  const int b = blockIdx.y;
  __shared__ __align__(16) float wlT[64 * 64];  // [g][o]
  for (int i = threadIdx.x; i < 4096; i += 256) {
    int o = i >> 6, g = i & 63;
    wlT[g * 64 + o] = M[b * 4096 + o * 64 + g];
  }
  __syncthreads();
  float acc[64];
#pragma unroll
  for (int o = 0; o < 64; ++o) acc[o] = 0.f;
  const float* vb = vconv + ((size_t)b * 64) * NPOS + p;
  for (int g = 0; g < 64; ++g) {
    float vv = vb[(size_t)g * NPOS];
    const float4* w4 = (const float4*)&wlT[g * 64];
#pragma unroll
    for (int o4 = 0; o4 < 16; ++o4) {
      float4 wv = w4[o4];
      acc[o4 * 4 + 0] = fmaf(wv.x, vv, acc[o4 * 4 + 0]);
      acc[o4 * 4 + 1] = fmaf(wv.y, vv, acc[o4 * 4 + 1]);
      acc[o4 * 4 + 2] = fmaf(wv.z, vv, acc[o4 * 4 + 2]);
      acc[o4 * 4 + 3] = fmaf(wv.w, vv, acc[o4 * 4 + 3]);
    }
  }
  float* ob = out + ((size_t)b * 64) * NPOS + p;
#pragma unroll
  for (int o = 0; o < 64; ++o) ob[(size_t)o * NPOS] = acc[o];
}

extern "C" void kernel_launch(void* const* d_in, const int* in_sizes, int n_in,
                              void* d_out, int out_size, void* d_ws, size_t ws_size,
                              hipStream_t stream) {
  const float* x      = (const float*)d_in[0];
  const float* w_qkv  = (const float*)d_in[1];
  const float* w_dw   = (const float*)d_in[2];
  const float* temp   = (const float*)d_in[3];
  const float* w_proj = (const float*)d_in[4];
  float* out = (float*)d_out;   // 2*64*131072 floats; also used as pre-conv staging
  float* ws  = (float*)d_ws;

  // workspace layout (floats) — total ~64.4 MiB
  float* conv_buf = ws;                       // 16,777,216  (qconv, later vconv)
  float* nqp      = conv_buf + 16777216ull;   // 8,192
  float* partial4 = nqp + 8192ull;            // 16*64*72 = 73,728
  float* Abuf     = partial4 + 73728ull;      // 1,024
  float* Mbuf     = Abuf + 1024ull;           // 8,192

  // q group: pointwise -> d_out, depthwise -> conv_buf (+ nq partials)
  k_pw<<<dim3(512, 2), 256, 0, stream>>>(x, w_qkv, out, 0);
  k_dw<<<dim3(4, 16, 128), dim3(32, 8), 0, stream>>>(out, w_dw, conv_buf, nqp, 0);
  // k group: pointwise -> d_out, depthwise fused with Gram vs qconv
  k_pw<<<dim3(512, 2), 256, 0, stream>>>(x, w_qkv, out, 1);
  k_dwk_gram<<<dim3(4, 16, 16), dim3(32, 8), 0, stream>>>(out, conv_buf, w_dw, partial4);
  // attention matrix + folded projection matrix
  k_attn<<<16, 128, 0, stream>>>(partial4, nqp, temp, Abuf);
  k_M<<<2, 256, 0, stream>>>(w_proj, Abuf, Mbuf);
  // v group: pointwise -> d_out, depthwise -> conv_buf, apply M -> d_out
  k_pw<<<dim3(512, 2), 256, 0, stream>>>(x, w_qkv, out, 2);
  k_dw<<<dim3(4, 16, 128), dim3(32, 8), 0, stream>>>(out, w_dw, conv_buf, nullptr, 2);
  k_out<<<dim3(512, 2), 256, 0, stream>>>(conv_buf, Mbuf, out);
}